// Round 10
// baseline (10.840 us; speedup 1.0000x reference)
//
#include <hip/hip_runtime.h>

// Problem constants (B, S, I, d) = (8, 32, 64, 256); L = S*I = 2048.
#define NB 8
#define L 2048
#define D 256
#define ROWV (D / 4)        // 64 float4-sized chunks per row
#define RPB 32              // rows per block (4 waves x 8 rows)
#define RPW 8               // rows per wave
#define NW (L / 64)         // 32 mask words per batch

// Native vector types (HIP_vector_type structs are rejected by
// __builtin_nontemporal_*).
typedef float f4 __attribute__((ext_vector_type(4)));
typedef int i4 __attribute__((ext_vector_type(4)));

// Payload is stream-once (no reuse): nontemporal loads/stores keep the 32 MB
// stream from evicting the (reused) mask out of L2. Mask loads stay cacheable.
static __device__ __forceinline__ f4 nt_load(const f4* p) {
    return __builtin_nontemporal_load(p);
}
static __device__ __forceinline__ void nt_store(f4* p, f4 v) {
    __builtin_nontemporal_store(v, p);
}

// Fused stable-compaction scatter, barrier-free. Each wave:
//  1. ballots its OWN mask word (its 8 rows share one 64-bit word),
//  2. issues 8 int4 mask-scan loads (whole batch, L1/L2-resident),
//  3. issues its 8 conditional payload loads,
//  4. counts {valid below word wi, valid total} from the int4 scan words —
//     threshold T = wi*64 is a multiple of 64, so the compare is uniform per
//     4-element chunk (4*lane < T - k*256) — then one packed shfl_xor
//     butterfly reduces both counts,
//  5. computes destinations and stores.
//   valid   l -> rank(l)                      (stable left-pack)
//   invalid l -> total_valid + (l - rank(l))  (stable tail; write zeros)
// Bijection on [0, L) => every output position written each call (d_out is
// poisoned once and never restored). No LDS, no __syncthreads.
__global__ void __launch_bounds__(256) compact_scatter(
    const f4* __restrict__ in, const int* __restrict__ mask,
    f4* __restrict__ out) {
    const int t = threadIdx.x;
    const int lane = t & 63;
    const int wid = t >> 6;                 // 0..3
    const int row0 = blockIdx.x * RPB;      // 32 rows per block, same batch
    const int batch = row0 >> 11;           // / L
    const int* m = mask + batch * L;

    const int lb0 = (row0 & (L - 1)) + wid * RPW;  // first row of this wave
    const int wi = lb0 >> 6;        // all 8 rows share one mask word (lb0 % 8 == 0)

    // Step 1: own-word ballot (no LDS, no sync needed).
    const unsigned long long cur = __ballot(m[wi * 64 + lane] != 0);

    // Step 2: issue the 8 vectorized mask-scan loads EARLY (named vars, no
    // consumption yet) so their vmcnt waits are not behind payload returns.
    const i4* m4 = (const i4*)m;    // 512 int4 per batch; lane-strided chunks
    const i4 w0 = m4[0 * 64 + lane];
    const i4 w1 = m4[1 * 64 + lane];
    const i4 w2 = m4[2 * 64 + lane];
    const i4 w3 = m4[3 * 64 + lane];
    const i4 w4 = m4[4 * 64 + lane];
    const i4 w5 = m4[5 * 64 + lane];
    const i4 w6 = m4[6 * 64 + lane];
    const i4 w7 = m4[7 * 64 + lane];

    const f4 z = (f4){0.f, 0.f, 0.f, 0.f};
    const size_t base = (size_t)batch * L;

    // Step 3: payload loads (val/lrank depend only on cur; wave-uniform
    // branches skip invalid rows entirely). Named scalars only (register
    // arrays crashed in R3/R4).
#define ROW_PRE(r)                                                          \
    const int bi##r = (lb0 + r) & 63;                                       \
    const bool val##r = (cur >> bi##r) & 1ull;                              \
    const int lrank##r = __popcll(cur & ((1ull << bi##r) - 1ull));          \
    f4 v##r = z;                                                            \
    if (val##r) v##r = nt_load(&in[(base + lb0 + r) * ROWV + lane]);

    ROW_PRE(0) ROW_PRE(1) ROW_PRE(2) ROW_PRE(3)
    ROW_PRE(4) ROW_PRE(5) ROW_PRE(6) ROW_PRE(7)
#undef ROW_PRE

    // Step 4: count valid below T and valid total; packed butterfly reduce.
    const int T = wi * 64;          // wave-uniform, multiple of 64
    int below = 0, all = 0;
#define CNT(k, wv)                                                          \
    {                                                                       \
        const int c = (wv.x != 0) + (wv.y != 0) + (wv.z != 0) + (wv.w != 0);\
        all += c;                                                           \
        if (4 * lane < T - k * 256) below += c;                             \
    }
    CNT(0, w0) CNT(1, w1) CNT(2, w2) CNT(3, w3)
    CNT(4, w4) CNT(5, w5) CNT(6, w6) CNT(7, w7)
#undef CNT

    int packed = below | (all << 16);   // both sums <= 2048: no field overflow
#pragma unroll
    for (int off = 1; off < 64; off <<= 1)
        packed += __shfl_xor(packed, off, 64);
    const int prefix = packed & 0xffff;
    const int total = packed >> 16;

    // Step 5: destinations + stores.
#define ROW_POST(r)                                                         \
    {                                                                       \
        const int rank = prefix + lrank##r;                                 \
        const int dest = val##r ? rank : (total + (lb0 + r - rank));        \
        nt_store(&out[(base + dest) * ROWV + lane], v##r);                  \
    }

    ROW_POST(0) ROW_POST(1) ROW_POST(2) ROW_POST(3)
    ROW_POST(4) ROW_POST(5) ROW_POST(6) ROW_POST(7)
#undef ROW_POST
}

extern "C" void kernel_launch(void* const* d_in, const int* in_sizes, int n_in,
                              void* d_out, int out_size, void* d_ws, size_t ws_size,
                              hipStream_t stream) {
    const float* ffn_out = (const float*)d_in[0];
    const int* valid_mask = (const int*)d_in[1];  // bool staged as int32 (nonzero = valid)
    float* out = (float*)d_out;

    compact_scatter<<<NB * L / RPB, 256, 0, stream>>>(
        (const f4*)ffn_out, valid_mask, (f4*)out);
}

// Round 11
// 10.745 us; speedup vs baseline: 1.0088x; 1.0088x over previous
//
#include <hip/hip_runtime.h>

// Problem constants (B, S, I, d) = (8, 32, 64, 256); L = S*I = 2048.
#define NB 8
#define L 2048
#define D 256
#define ROWV (D / 4)        // 64 float4-sized chunks per row
#define RPB 32              // rows per block (4 waves x 8 rows)
#define RPW 8               // rows per wave
#define NW (L / 64)         // 32 mask words per batch

// Native vector type: __builtin_nontemporal_* rejects HIP_vector_type
// (struct), but accepts clang ext_vector_type.
typedef float f4 __attribute__((ext_vector_type(4)));

// Payload is stream-once (no reuse): nontemporal loads/stores keep the 32 MB
// stream from evicting the (reused) mask out of L2. Mask loads stay cacheable.
static __device__ __forceinline__ f4 nt_load(const f4* p) {
    return __builtin_nontemporal_load(p);
}
static __device__ __forceinline__ void nt_store(f4* p, f4 v) {
    __builtin_nontemporal_store(v, p);
}

// Fused stable-compaction scatter, barrier-free (R7 structure). Each wave:
//  1. ballots its OWN mask word (its 8 rows share one 64-bit word),
//  2. immediately issues its 8 conditional payload loads (overlap),
//  3. re-ballots all 32 words of the batch (L1/L2-resident mask) to get
//     prefix (valid count below its word) and total (batch valid count),
//  4. computes destinations and stores.
//   valid   l -> rank(l)                      (stable left-pack)
//   invalid l -> total_valid + (l - rank(l))  (stable tail; write zeros)
// Bijection on [0, L) => every output position written each call (d_out is
// poisoned once and never restored).
__global__ void __launch_bounds__(256) compact_scatter(
    const f4* __restrict__ in, const int* __restrict__ mask,
    f4* __restrict__ out) {
    const int t = threadIdx.x;
    const int lane = t & 63;
    const int wid = t >> 6;                 // 0..3
    const int row0 = blockIdx.x * RPB;      // 32 rows per block, same batch
    const int batch = row0 >> 11;           // / L
    const int* m = mask + batch * L;

    const int lb0 = (row0 & (L - 1)) + wid * RPW;  // first row of this wave
    const int wi = lb0 >> 6;        // all 8 rows share one mask word (lb0 % 8 == 0)

    // Step 1: own-word ballot (no LDS, no sync needed).
    const unsigned long long cur = __ballot(m[wi * 64 + lane] != 0);

    const f4 z = (f4){0.f, 0.f, 0.f, 0.f};
    const size_t base = (size_t)batch * L;

    // Step 2: issue payload loads NOW (val/lrank depend only on cur).
    // Named scalars only (register arrays crashed in R3/R4).
#define ROW_PRE(r)                                                          \
    const int bi##r = (lb0 + r) & 63;                                       \
    const bool val##r = (cur >> bi##r) & 1ull;                              \
    const int lrank##r = __popcll(cur & ((1ull << bi##r) - 1ull));          \
    f4 v##r = z;                                                            \
    if (val##r) v##r = nt_load(&in[(base + lb0 + r) * ROWV + lane]);

    ROW_PRE(0) ROW_PRE(1) ROW_PRE(2) ROW_PRE(3)
    ROW_PRE(4) ROW_PRE(5) ROW_PRE(6) ROW_PRE(7)
#undef ROW_PRE

    // Step 3: full-batch scan via ballots (mask is L1/L2-resident; this
    // VALU/L2 work overlaps the in-flight payload loads above).
    int prefix = 0, total = 0;
#pragma unroll
    for (int w = 0; w < NW; ++w) {
        const unsigned long long bw = __ballot(m[w * 64 + lane] != 0);
        const int pc = __popcll(bw);
        total += pc;
        if (w < wi) prefix += pc;   // wi is wave-uniform -> scalar branch
    }

    // Step 4: destinations + stores.
#define ROW_POST(r)                                                         \
    {                                                                       \
        const int rank = prefix + lrank##r;                                 \
        const int dest = val##r ? rank : (total + (lb0 + r - rank));        \
        nt_store(&out[(base + dest) * ROWV + lane], v##r);                  \
    }

    ROW_POST(0) ROW_POST(1) ROW_POST(2) ROW_POST(3)
    ROW_POST(4) ROW_POST(5) ROW_POST(6) ROW_POST(7)
#undef ROW_POST
}

extern "C" void kernel_launch(void* const* d_in, const int* in_sizes, int n_in,
                              void* d_out, int out_size, void* d_ws, size_t ws_size,
                              hipStream_t stream) {
    const float* ffn_out = (const float*)d_in[0];
    const int* valid_mask = (const int*)d_in[1];  // bool staged as int32 (nonzero = valid)
    float* out = (float*)d_out;

    compact_scatter<<<NB * L / RPB, 256, 0, stream>>>(
        (const f4*)ffn_out, valid_mask, (f4*)out);
}